// Round 8
// baseline (117.983 us; speedup 1.0000x reference)
//
#include <hip/hip_runtime.h>
#include <hip/hip_bf16.h>
#include <stdint.h>

typedef unsigned short u16;
typedef short short8 __attribute__((ext_vector_type(8)));
typedef float f32x4 __attribute__((ext_vector_type(4)));

#define SEQ 2048
#define EMB 1024
#define NH 16
#define HD 64
#define ZP 2112  // SEQ + 64 pad, reversed z per (b,h)

__device__ inline u16 f2bf(float f) {
    uint32_t u = __builtin_bit_cast(uint32_t, f);
    uint32_t r = (u + 0x7FFFu + ((u >> 16) & 1u)) >> 16;
    return (u16)r;
}

__device__ inline void gload16(const void* g, void* l) {
    __builtin_amdgcn_global_load_lds(
        (const __attribute__((address_space(1))) void*)g,
        (__attribute__((address_space(3))) void*)l, 16, 0, 0);
}

// ---------------- all casts fused: x, W_V, W_O fp32 -> bf16 ----------------
__global__ __launch_bounds__(256) void cast_all(const float* __restrict__ x,
                                                const float* __restrict__ W_V,
                                                const float* __restrict__ W_O,
                                                u16* __restrict__ xb,
                                                u16* __restrict__ wvb,
                                                u16* __restrict__ wob) {
    int bid = blockIdx.x, t = threadIdx.x;
    const float* src;
    u16* dst;
    int j;
    if (bid < 4096) { j = bid * 256 + t; src = x; dst = xb; }
    else {
        j = (bid - 4096) * 256 + t;
        if (j < 262144) { src = W_V; dst = wvb; }
        else { j -= 262144; src = W_O; dst = wob; }
    }
    float4 f = reinterpret_cast<const float4*>(src)[j];
    union { u16 u[4]; uint2 v; } o;
    o.u[0] = f2bf(f.x); o.u[1] = f2bf(f.y); o.u[2] = f2bf(f.z); o.u[3] = f2bf(f.w);
    reinterpret_cast<uint2*>(dst)[j] = o.v;
}

// ---------------- logits: zl[b][h][s] = dot(x[b,s,:], W_A[h,:]) * 0.125 ----------------
__global__ __launch_bounds__(256) void logits_kernel(const float* __restrict__ x,
                                                     const float* __restrict__ W_A,
                                                     float* __restrict__ zl) {
    __shared__ float wa[NH * EMB]; // 64 KB
    int t = threadIdx.x;
    for (int i = t; i < NH * EMB / 4; i += 256)
        reinterpret_cast<float4*>(wa)[i] = reinterpret_cast<const float4*>(W_A)[i];
    __syncthreads();
    int w = t >> 6, l = t & 63;
    int row0 = blockIdx.x * 16 + w * 4;
    for (int rr = 0; rr < 4; rr++) {
        int gs = row0 + rr;           // 0..4095 = b*SEQ + s
        int b = gs >> 11, s = gs & 2047;
        const float* xr = x + (size_t)gs * EMB;
        float xv[16];
#pragma unroll
        for (int q = 0; q < 16; q++) xv[q] = xr[l + 64 * q];
#pragma unroll
        for (int h = 0; h < NH; h++) {
            float a = 0.f;
#pragma unroll
            for (int q = 0; q < 16; q++) a += xv[q] * wa[h * EMB + l + 64 * q];
#pragma unroll
            for (int off = 32; off; off >>= 1) a += __shfl_xor(a, off);
            if (l == h) zl[((size_t)b * NH + h) * SEQ + s] = a * 0.125f;
        }
    }
}

// ---------------- softmax body (per bh), 256 threads ----------------
__device__ void softmax_body(const float* __restrict__ zl, u16* __restrict__ zr, int bh) {
    const float* src = zl + (size_t)bh * SEQ;
    int t = threadIdx.x;
    int w = t >> 6, l = t & 63;
    __shared__ float red4[4];
    __shared__ float bc;
    float v[8];
#pragma unroll
    for (int q = 0; q < 8; q++) v[q] = src[t + 256 * q];
    float m = v[0];
#pragma unroll
    for (int q = 1; q < 8; q++) m = fmaxf(m, v[q]);
#pragma unroll
    for (int off = 32; off; off >>= 1) m = fmaxf(m, __shfl_xor(m, off));
    if (l == 0) red4[w] = m;
    __syncthreads();
    if (t == 0) bc = fmaxf(fmaxf(red4[0], red4[1]), fmaxf(red4[2], red4[3]));
    __syncthreads();
    m = bc;
    float s = 0.f;
#pragma unroll
    for (int q = 0; q < 8; q++) { v[q] = expf(v[q] - m); s += v[q]; }
#pragma unroll
    for (int off = 32; off; off >>= 1) s += __shfl_xor(s, off);
    if (l == 0) red4[w] = s;
    __syncthreads();
    if (t == 0) bc = red4[0] + red4[1] + red4[2] + red4[3];
    __syncthreads();
    float inv = 1.0f / bc;
#pragma unroll
    for (int q = 0; q < 8; q++) {
        int sidx = t + 256 * q;
        zr[(size_t)bh * ZP + (SEQ - 1 - sidx)] = f2bf(v[q] * inv);
    }
    if (t < ZP - SEQ) zr[(size_t)bh * ZP + SEQ + t] = 0;
}

// ---------------- GEMM: C[M,N] = A[M,K] * B[N,K]^T, in-block K-split ----------------
// 64x64 output tile, 256 threads = 4 waves; wave w computes the FULL 64x64 tile
// over k in [w*K/4, (w+1)*K/4). Grid = (M/64)*(N/64) = 1024 blocks -> 4 blocks/CU.
// Staging (rule #21 compliant): each gload16 call is one contiguous 1KiB
// wave-write -- dest base is WAVE-UNIFORM ((w*16+q*4)*128 u16); lane l lands
// linearly at row +(l>>4), chunk (l&15). The XOR swizzle C = cp ^ (row&15)
// is applied on the PER-LANE GLOBAL SOURCE address. Compute-side ds_read uses
// LDS chunk ((w*4+lk) ^ lrow) -> 2-way bank aliasing (free, m136).
// Epilogue: 4-barrier LDS fp32 reduction of the 4 waves' partials, then
// coalesced store. OUTMODE 0: bf16 out; 1: fp32 out + bias.
// SM: blocks >= gemmBlocks run softmax (fused independent work).
template <int OUTMODE, int MAP, bool SM>
__global__ __launch_bounds__(256, 4) void gemm_ks(const u16* __restrict__ A,
                                                  const u16* __restrict__ Bw,
                                                  u16* __restrict__ Cb, float* __restrict__ Cf,
                                                  const float* __restrict__ bias,
                                                  int M, int N, int K,
                                                  const float* __restrict__ zl,
                                                  u16* __restrict__ zr) {
    const int nblk = (M >> 6) * (N >> 6);
    if constexpr (SM) {
        if ((int)blockIdx.x >= nblk) { softmax_body(zl, zr, blockIdx.x - nblk); return; }
    }
    __shared__ float red[2][64][68];           // 34816 B; staging aliases into it
    u16* As = (u16*)&red[0][0][0];             // [64][128] u16 = 16 KB
    u16* Bs = As + 8192;                       // [64][128] u16 = 16 KB

    const int t = threadIdx.x;
    const int i = blockIdx.x;
    const int cpx = nblk >> 3;
    const int wg = (i & 7) * cpx + (i >> 3);   // XCD-chunked, bijective (nblk%8==0)
    int xg, yg;
    if constexpr (MAP == 0) { xg = wg >> 4; yg = wg & 15; }
    else                    { yg = wg >> 4; xg = wg & 15; }
    const int m0 = yg * 64, n0 = xg * 64;
    const int w = t >> 6, l = t & 63;
    const int lrow = l & 15, lk = l >> 4;
    const int Kq = K >> 2;                     // per-wave K range

    // ---- staging setup: wave w stages rows w*16..w*16+15 (4 calls x 4 rows) ----
    const u16* sA[4];
    const u16* sB[4];
    int db[4];
#pragma unroll
    for (int q = 0; q < 4; q++) {
        int row = w * 16 + q * 4 + (l >> 4);   // this lane's staged row
        int cp = l & 15;                       // this lane's LDS chunk16
        int C = cp ^ (row & 15);               // logical (source) chunk
        int kb = (C >> 2) * Kq + (C & 3) * 8;  // + s*32 per step
        sA[q] = A + (size_t)(m0 + row) * K + kb;
        sB[q] = Bw + (size_t)(n0 + row) * K + kb;
        db[q] = (w * 16 + q * 4) * 128;        // WAVE-UNIFORM dest base (u16)
    }
    // ---- compute-side LDS read offsets (loop-invariant) ----
    int ro[4];
#pragma unroll
    for (int mi = 0; mi < 4; mi++)
        ro[mi] = (mi * 16 + lrow) * 128 + (((w * 4 + lk) ^ lrow) * 8);

    f32x4 acc[4][4];
#pragma unroll
    for (int a = 0; a < 4; a++)
#pragma unroll
        for (int b = 0; b < 4; b++) acc[a][b] = (f32x4){0.f, 0.f, 0.f, 0.f};

    const int NS = Kq >> 5;                    // sync steps (8 for K=1024)
    for (int s = 0; s < NS; s++) {
        const int ko = s * 32;
#pragma unroll
        for (int q = 0; q < 4; q++) gload16(sA[q] + ko, As + db[q]);
#pragma unroll
        for (int q = 0; q < 4; q++) gload16(sB[q] + ko, Bs + db[q]);
        __syncthreads();                       // drains vmcnt -> slab resident
        short8 af[4], bf[4];
#pragma unroll
        for (int mi = 0; mi < 4; mi++)
            af[mi] = *reinterpret_cast<const short8*>(&As[ro[mi]]);
#pragma unroll
        for (int ni = 0; ni < 4; ni++)
            bf[ni] = *reinterpret_cast<const short8*>(&Bs[ro[ni]]);
#pragma unroll
        for (int mi = 0; mi < 4; mi++)
#pragma unroll
            for (int ni = 0; ni < 4; ni++)
                acc[mi][ni] = __builtin_amdgcn_mfma_f32_16x16x32_bf16(af[mi], bf[ni], acc[mi][ni], 0, 0, 0);
        __syncthreads();                       // reads done before next overwrite
    }

    // ---- reduction of 4 waves' partials ----
    auto dump = [&](int slot) {
#pragma unroll
        for (int mi = 0; mi < 4; mi++)
#pragma unroll
            for (int ni = 0; ni < 4; ni++)
#pragma unroll
                for (int rr = 0; rr < 4; rr++)
                    red[slot][mi * 16 + lk * 4 + rr][ni * 16 + lrow] = acc[mi][ni][rr];
    };
    auto addin = [&](int slot) {
#pragma unroll
        for (int mi = 0; mi < 4; mi++)
#pragma unroll
            for (int ni = 0; ni < 4; ni++)
#pragma unroll
                for (int rr = 0; rr < 4; rr++)
                    acc[mi][ni][rr] += red[slot][mi * 16 + lk * 4 + rr][ni * 16 + lrow];
    };
    if (w == 1) dump(0);
    if (w == 3) dump(1);
    __syncthreads();
    if (w == 0) addin(0);
    if (w == 2) addin(1);
    __syncthreads();
    if (w == 2) dump(0);
    __syncthreads();
    if (w == 0) { addin(0); dump(0); }
    __syncthreads();

    // ---- coalesced store: thread t -> row t>>2, cols (t&3)*16 .. +15 ----
    const int sr = t >> 2, sc = (t & 3) * 16;
    if constexpr (OUTMODE == 0) {
        union { u16 u[16]; uint4 v[2]; } o;
#pragma unroll
        for (int j = 0; j < 16; j++) o.u[j] = f2bf(red[0][sr][sc + j]);
        uint4* p = reinterpret_cast<uint4*>(Cb + (size_t)(m0 + sr) * N + n0 + sc);
        p[0] = o.v[0];
        p[1] = o.v[1];
    } else {
        float o[16];
#pragma unroll
        for (int j = 0; j < 16; j++) o[j] = red[0][sr][sc + j] + bias[n0 + sc + j];
        float4* p = reinterpret_cast<float4*>(Cf + (size_t)(m0 + sr) * N + n0 + sc);
#pragma unroll
        for (int j4 = 0; j4 < 4; j4++)
            p[j4] = (float4){o[j4 * 4], o[j4 * 4 + 1], o[j4 * 4 + 2], o[j4 * 4 + 3]};
    }
}

// ---------------- causal Toeplitz conv, barrier-free ----------------
// out[b,i,h,:] = sum_{j<=i} z[b,h,i-j] * v[b,j,h,:]
// A[row][k] = zrev[2047-row+k]: fragments read directly from dual-parity LDS
// copies of zrev; B fragments from v^T in global (L2-resident via XCD swizzle).
// 2048 wave-tasks: (bh, slice-pair (s,63-s) of 32 rows, col-half); 65 K32-steps
// each (uniform). 512 blocks -> 2 waves/SIMD. Depth-2 B prefetch (static names).
__global__ __launch_bounds__(256) void conv_kernel(const u16* __restrict__ zr,
                                                   const u16* __restrict__ vt2,
                                                   u16* __restrict__ cv) {
    const int i = blockIdx.x;
    const int bh = (i & 7) * 4 + ((i >> 3) & 3);
    const int rest = i >> 5;                   // 0..15
    const int b = bh >> 4, h = bh & 15;
    __shared__ uint zsl[2176];  // [0..1087]=zrev dwords, [1088..]=shift-by-1-elem
    const int t = threadIdx.x;
    {
        const uint* zp = reinterpret_cast<const uint*>(zr + (size_t)bh * ZP);
        for (int q = t; q < 1088; q += 256) {
            uint v0 = (q < 1056) ? zp[q] : 0u;
            uint v1 = (q < 1055) ? zp[q + 1] : 0u;
            zsl[q] = v0;
            zsl[1088 + q] = (v0 >> 16) | (v1 << 16);
        }
    }
    __syncthreads();

    const int w = t >> 6, l = t & 63;
    const int task = rest * 4 + w;             // 0..63
    const int pp = task >> 1;                  // 0..31
    const int ch = task & 1;
    const int lrow = l & 15;
    const int lk8 = (l >> 4) * 8;
    const int col0 = ch * 32;
    const int ebase = h * 64 + col0;
    const size_t boff = (size_t)b * SEQ;

    union U { uint d[4]; short8 s8; };

    int slices[2] = {pp, 63 - pp};
#pragma unroll 1
    for (int si = 0; si < 2; si++) {
        const int s = slices[si];
        const int row0 = s * 32;
        const int nk = s + 1;                  // K32 steps
        f32x4 acc[2][2];
#pragma unroll
        for (int a = 0; a < 2; a++)
#pragma unroll
            for (int c = 0; c < 2; c++) acc[a][c] = (f32x4){0.f, 0.f, 0.f, 0.f};

        const int obase = 2047 - row0 - lrow + lk8;

        auto loadB = [&](int k0, U* bf) {
#pragma unroll
            for (int ni = 0; ni < 2; ni++) {
                const u16* p = vt2 + (((size_t)(ebase + ni * 16 + lrow)) << 12) + boff + k0 + lk8;
                *reinterpret_cast<uint4*>(bf[ni].d) = *reinterpret_cast<const uint4*>(p);
            }
        };
        auto loadA = [&](int k0, U* af) {
#pragma unroll
            for (int mi = 0; mi < 2; mi++) {
                int o = obase - mi * 16 + k0;
                uint adw = (uint)(o >> 1) + (uint)((o & 1) * 1088);
#pragma unroll
                for (int q = 0; q < 4; q++) af[mi].d[q] = zsl[adw + q];
            }
        };

        U a0[2], a1[2], b0[2], b1[2];
        loadB(0, b0);
        loadB(32, b1);          // harmless over-read if nk==1 (in-bounds)
        loadA(0, a0);
        int k = 0;
        for (; k + 1 < nk; k += 2) {
            loadA((k + 1) * 32, a1);
#pragma unroll
            for (int mi = 0; mi < 2; mi++)
#pragma unroll
                for (int ni = 0; ni < 2; ni++)
                    acc[mi][ni] = __builtin_amdgcn_mfma_f32_16x16x32_bf16(a0[mi].s8, b0[ni].s8, acc[mi][ni], 0, 0, 0);
            if (k + 2 < nk) loadB((k + 2) * 32, b0);
            loadA((k + 2) * 32, a0);   // over-read stays inside zsl (pad analyzed)
#pragma unroll
            for (int mi = 0; mi < 2; mi++)
#pragma unroll
                for (int ni = 0; ni < 2; ni++)
                    acc[mi][ni] = __builtin_amdgcn_mfma_f32_16x16x32_bf16(a1[mi].s8, b1[ni].s8, acc[mi][ni], 0, 0, 0);
            if (k + 3 < nk) loadB((k + 3) * 32, b1);
        }
        if (nk & 1) {
#pragma unroll
            for (int mi = 0; mi < 2; mi++)
#pragma unroll
                for (int ni = 0; ni < 2; ni++)
                    acc[mi][ni] = __builtin_amdgcn_mfma_f32_16x16x32_bf16(a0[mi].s8, b0[ni].s8, acc[mi][ni], 0, 0, 0);
        }
#pragma unroll
        for (int mi = 0; mi < 2; mi++)
#pragma unroll
            for (int ni = 0; ni < 2; ni++)
#pragma unroll
                for (int rr = 0; rr < 4; rr++) {
                    int row = row0 + mi * 16 + (l >> 4) * 4 + rr;
                    int col = col0 + ni * 16 + lrow;
                    cv[((size_t)b * SEQ + row) * EMB + h * 64 + col] = f2bf(acc[mi][ni][rr]);
                }
    }
}

extern "C" void kernel_launch(void* const* d_in, const int* in_sizes, int n_in,
                              void* d_out, int out_size, void* d_ws, size_t ws_size,
                              hipStream_t stream) {
    const float* x   = (const float*)d_in[0];
    const float* W_A = (const float*)d_in[1];
    const float* W_V = (const float*)d_in[2];
    const float* W_O = (const float*)d_in[3];
    const float* b_O = (const float*)d_in[4];

    char* ws = (char*)d_ws;
    u16*   xb  = (u16*)(ws + 0);          // 8 MB   x bf16 [4096][1024]
    u16*   wvb = (u16*)(ws + 8388608);    // 2 MB   W_V bf16 [1024][1024]
    u16*   wob = (u16*)(ws + 10485760);   // 2 MB   W_O bf16
    float* zl  = (float*)(ws + 12582912); // 256 KB logits fp32 [B][H][S]
    u16*   zr  = (u16*)(ws + 12845056);   // 132 KB reversed softmax bf16 [B][H][ZP]
    u16*   vt2 = (u16*)(ws + 12980224);   // 8 MB   v^T bf16 [1024][B*S]
    u16*   cv  = (u16*)(ws + 21368832);   // 8 MB   conv out bf16 [4096][1024]

    cast_all<<<6144, 256, 0, stream>>>(x, W_V, W_O, xb, wvb, wob);
    logits_kernel<<<256, 256, 0, stream>>>(x, W_A, zl);
    // v^T[e][b*S+s] = sum_k W_V[e,k] * x[b,s,k]; blocks 1024..1055 do softmax
    gemm_ks<0, 0, true><<<1056, 256, 0, stream>>>(wvb, xb, vt2, nullptr, nullptr,
                                                  1024, 4096, 1024, zl, zr);
    conv_kernel<<<512, 256, 0, stream>>>(zr, vt2, cv);
    gemm_ks<1, 1, false><<<1024, 256, 0, stream>>>(cv, wob, nullptr, (float*)d_out, b_O,
                                                   4096, 1024, 1024, nullptr, nullptr);
}

// Round 9
// 99.890 us; speedup vs baseline: 1.1811x; 1.1811x over previous
//
#include <hip/hip_runtime.h>
#include <hip/hip_bf16.h>
#include <stdint.h>

typedef unsigned short u16;
typedef short short8 __attribute__((ext_vector_type(8)));
typedef float f32x4 __attribute__((ext_vector_type(4)));

#define SEQ 2048
#define EMB 1024
#define NH 16
#define HD 64
#define ZP 2112  // SEQ + 64 pad, reversed z per (b,h)

__device__ inline u16 f2bf(float f) {
    uint32_t u = __builtin_bit_cast(uint32_t, f);
    uint32_t r = (u + 0x7FFFu + ((u >> 16) & 1u)) >> 16;
    return (u16)r;
}

__device__ inline void gload16(const void* g, void* l) {
    __builtin_amdgcn_global_load_lds(
        (const __attribute__((address_space(1))) void*)g,
        (__attribute__((address_space(3))) void*)l, 16, 0, 0);
}

// ---------------- fused: x cast->bf16 + logits; W_V/W_O cast in tail blocks ----------------
// blocks 0..255: 16 x-rows each -- load fp32 row once, store bf16, compute 16 head-dots.
// blocks 256..2303: W_V then W_O fp32->bf16 (float4 granularity).
__global__ __launch_bounds__(256) void cast_logits(const float* __restrict__ x,
                                                   const float* __restrict__ W_A,
                                                   const float* __restrict__ W_V,
                                                   const float* __restrict__ W_O,
                                                   u16* __restrict__ xb,
                                                   u16* __restrict__ wvb,
                                                   u16* __restrict__ wob,
                                                   float* __restrict__ zl) {
    const int bid = blockIdx.x, t = threadIdx.x;
    if (bid >= 256) {
        int j = (bid - 256) * 256 + t;
        const float* src;
        u16* dst;
        if (j < 262144) { src = W_V; dst = wvb; }
        else { j -= 262144; src = W_O; dst = wob; }
        float4 f = reinterpret_cast<const float4*>(src)[j];
        union { u16 u[4]; uint2 v; } o;
        o.u[0] = f2bf(f.x); o.u[1] = f2bf(f.y); o.u[2] = f2bf(f.z); o.u[3] = f2bf(f.w);
        reinterpret_cast<uint2*>(dst)[j] = o.v;
        return;
    }
    __shared__ float wa[NH * EMB]; // 64 KB
    for (int i = t; i < NH * EMB / 4; i += 256)
        reinterpret_cast<float4*>(wa)[i] = reinterpret_cast<const float4*>(W_A)[i];
    __syncthreads();
    const int w = t >> 6, l = t & 63;
    const int row0 = bid * 16 + w * 4;
    for (int rr = 0; rr < 4; rr++) {
        int gs = row0 + rr;           // 0..4095 = b*SEQ + s
        int b = gs >> 11, s = gs & 2047;
        const float* xr = x + (size_t)gs * EMB;
        float xv[16];
#pragma unroll
        for (int q = 0; q < 16; q++) xv[q] = xr[l + 64 * q];
        u16* xw = xb + (size_t)gs * EMB;
#pragma unroll
        for (int q = 0; q < 16; q++) xw[l + 64 * q] = f2bf(xv[q]);
#pragma unroll
        for (int h = 0; h < NH; h++) {
            float a = 0.f;
#pragma unroll
            for (int q = 0; q < 16; q++) a += xv[q] * wa[h * EMB + l + 64 * q];
#pragma unroll
            for (int off = 32; off; off >>= 1) a += __shfl_xor(a, off);
            if (l == h) zl[((size_t)b * NH + h) * SEQ + s] = a * 0.125f;
        }
    }
}

// ---------------- softmax body (per bh), 256 threads ----------------
__device__ void softmax_body(const float* __restrict__ zl, u16* __restrict__ zr, int bh) {
    const float* src = zl + (size_t)bh * SEQ;
    int t = threadIdx.x;
    int w = t >> 6, l = t & 63;
    __shared__ float red4[4];
    __shared__ float bc;
    float v[8];
#pragma unroll
    for (int q = 0; q < 8; q++) v[q] = src[t + 256 * q];
    float m = v[0];
#pragma unroll
    for (int q = 1; q < 8; q++) m = fmaxf(m, v[q]);
#pragma unroll
    for (int off = 32; off; off >>= 1) m = fmaxf(m, __shfl_xor(m, off));
    if (l == 0) red4[w] = m;
    __syncthreads();
    if (t == 0) bc = fmaxf(fmaxf(red4[0], red4[1]), fmaxf(red4[2], red4[3]));
    __syncthreads();
    m = bc;
    float s = 0.f;
#pragma unroll
    for (int q = 0; q < 8; q++) { v[q] = expf(v[q] - m); s += v[q]; }
#pragma unroll
    for (int off = 32; off; off >>= 1) s += __shfl_xor(s, off);
    if (l == 0) red4[w] = s;
    __syncthreads();
    if (t == 0) bc = red4[0] + red4[1] + red4[2] + red4[3];
    __syncthreads();
    float inv = 1.0f / bc;
#pragma unroll
    for (int q = 0; q < 8; q++) {
        int sidx = t + 256 * q;
        zr[(size_t)bh * ZP + (SEQ - 1 - sidx)] = f2bf(v[q] * inv);
    }
    if (t < ZP - SEQ) zr[(size_t)bh * ZP + SEQ + t] = 0;
}

// ---------------- GEMM: C[M,N] = A[M,K] * B[N,K]^T (R5 structure, best measured) -------------
// 128x64 tile, 256 threads (4 waves, 2x2), BK=64, double-buffered, 2-phase.
// XCD swizzle: MAP 0 groups same-x (share B panel), MAP 1 groups same-y (share A).
// SM: blocks >= 512 run softmax instead (fused independent work).
// OUTMODE 0: bf16 out; 1: fp32 out + bias
template <int OUTMODE, int MAP, bool SM>
__global__ __launch_bounds__(256) void gemm64(const u16* __restrict__ A,
                                              const u16* __restrict__ Bw,
                                              u16* __restrict__ Cb, float* __restrict__ Cf,
                                              const float* __restrict__ bias,
                                              int M, int N, int K,
                                              const float* __restrict__ zl,
                                              u16* __restrict__ zr) {
    if constexpr (SM) {
        if (blockIdx.x >= 512) { softmax_body(zl, zr, blockIdx.x - 512); return; }
    }
    __shared__ u16 As[2][128 * 64];
    __shared__ u16 Bs[2][64 * 64];
    const int t = threadIdx.x;
    const int i = blockIdx.x;
    int xg, yg;
    if constexpr (MAP == 0) { xg = (i & 7) * 8 + ((i >> 3) & 7); yg = i >> 6; }
    else                    { yg = (i & 7) * 4 + ((i >> 3) & 3); xg = i >> 5; }
    const int m0 = yg * 128, n0 = xg * 64;
    const int w = t >> 6, l = t & 63;
    const int wr = w >> 1, wc = w & 1;       // wave tile 64 rows x 32 cols
    const int lrow = l & 15, lk = l >> 4;
    const int r7 = lrow & 7;

    const int srow = t >> 3;                  // 0..31
    const int scb = ((t & 7) ^ ((t >> 3) & 7)) * 8;
    const u16* gA = A + (size_t)(m0 + srow) * K + scb;
    const u16* gB = Bw + (size_t)(n0 + srow) * K + scb;
    const int ldst = w * 512;

    f32x4 acc[4][2];
#pragma unroll
    for (int a = 0; a < 4; a++)
#pragma unroll
        for (int b = 0; b < 2; b++) acc[a][b] = (f32x4){0.f, 0.f, 0.f, 0.f};

    const int NT = K >> 6;
    const size_t rk32 = (size_t)32 * K;
#pragma unroll
    for (int c = 0; c < 4; c++) gload16(gA + c * rk32, &As[0][ldst + 2048 * c]);
#pragma unroll
    for (int c = 0; c < 2; c++) gload16(gB + c * rk32, &Bs[0][ldst + 2048 * c]);
    __syncthreads();

    for (int kt = 0; kt < NT; kt++) {
        const int cur = kt & 1;
        if (kt + 1 < NT) {
            const int k0 = (kt + 1) * 64;
#pragma unroll
            for (int c = 0; c < 4; c++) gload16(gA + k0 + c * rk32, &As[cur ^ 1][ldst + 2048 * c]);
#pragma unroll
            for (int c = 0; c < 2; c++) gload16(gB + k0 + c * rk32, &Bs[cur ^ 1][ldst + 2048 * c]);
        }
#pragma unroll
        for (int kk = 0; kk < 2; kk++) {
            const int cs = ((kk * 4 + lk) ^ r7) * 8;
            short8 af[4], bf2[2];
#pragma unroll
            for (int mi = 0; mi < 4; mi++)
                af[mi] = *reinterpret_cast<const short8*>(
                    &As[cur][(wr * 64 + mi * 16 + lrow) * 64 + cs]);
#pragma unroll
            for (int ni = 0; ni < 2; ni++)
                bf2[ni] = *reinterpret_cast<const short8*>(
                    &Bs[cur][(wc * 32 + ni * 16 + lrow) * 64 + cs]);
#pragma unroll
            for (int mi = 0; mi < 4; mi++)
#pragma unroll
                for (int ni = 0; ni < 2; ni++)
                    acc[mi][ni] = __builtin_amdgcn_mfma_f32_16x16x32_bf16(af[mi], bf2[ni], acc[mi][ni], 0, 0, 0);
        }
        __syncthreads();
    }
#pragma unroll
    for (int mi = 0; mi < 4; mi++)
#pragma unroll
        for (int ni = 0; ni < 2; ni++)
#pragma unroll
            for (int r = 0; r < 4; r++) {
                int row = m0 + wr * 64 + mi * 16 + lk * 4 + r;
                int col = n0 + wc * 32 + ni * 16 + lrow;
                if constexpr (OUTMODE == 0)
                    Cb[(size_t)row * N + col] = f2bf(acc[mi][ni][r]);
                else
                    Cf[(size_t)row * N + col] = acc[mi][ni][r] + bias[col];
            }
}

// ---------------- causal Toeplitz conv, shared B-tile ----------------
// out[b,i,h,:] = sum_{j<=i} z[b,h,i-j] * v[b,j,h,:];  A[i][k] = zrev[2047-i+k].
// Block = (bh, ch=32 e-cols, row-pair groups g & 7-g of 256 rows each).
// B-tile [32 e][64 k] staged ONCE per k-step in LDS (dbuf, wave-uniform gload16
// dest, XOR-swizzled per-lane SOURCE; read chunk ^= row&7 -> 2-way = free) and
// shared by all 4 waves -> ~8x less L2 traffic than per-wave global B reads.
// A fragments read from dual-parity zrev LDS (no A tile). 36 uniform steps/block.
// Per-wave k-guard keeps barriers block-uniform.
__global__ __launch_bounds__(256) void conv2(const u16* __restrict__ zr,
                                             const u16* __restrict__ vt2,
                                             u16* __restrict__ cv) {
    const int i = blockIdx.x;
    const int bh = (i & 7) * 4 + ((i >> 3) & 3);   // 4 bh per XCD
    const int rest = i >> 5;                        // 0..7
    const int ch = rest & 1;
    const int gsel = rest >> 1;                     // 0..3
    const int b = bh >> 4, h = bh & 15;
    __shared__ uint zsl[2176];       // dual-parity zrev (8.5 KB)
    __shared__ u16 Bt[2][32 * 64];   // B tile dbuf (8 KB)
    const int t = threadIdx.x;
    {
        const uint* zp = reinterpret_cast<const uint*>(zr + (size_t)bh * ZP);
        for (int q = t; q < 1088; q += 256) {
            uint v0 = (q < 1056) ? zp[q] : 0u;
            uint v1 = (q < 1055) ? zp[q + 1] : 0u;
            zsl[q] = v0;
            zsl[1088 + q] = (v0 >> 16) | (v1 << 16);
        }
    }
    const int w = t >> 6, l = t & 63;
    const int lrow = l & 15, lk = l >> 4, lk8 = lk * 8;
    const int ebase = h * 64 + ch * 32;
    const size_t boff = (size_t)b * SEQ;

    // staging: lane sources tile row rB, logical chunk cp^(rB&7); dest wave-uniform
    const int rB = w * 8 + (l >> 3);
    const int Csrc = (l & 7) ^ (rB & 7);
    const u16* gB = vt2 + (((size_t)(ebase + rB)) << 12) + boff + Csrc * 8;
    const int dbase = w * 512;                      // u16 units
    __syncthreads();                                // zsl ready

    union U { uint d[4]; short8 s8; };
    const int gms[2] = {gsel, 7 - gsel};
#pragma unroll 1
    for (int si = 0; si < 2; si++) {
        const int gm = gms[si];
        const int kend = (gm + 1) * 256;
        const int ns = kend >> 6;
        const int r0 = gm * 256 + w * 64;           // this wave's 64 rows
        const int wkmax = r0 + 64;
        const int obase0 = 2047 - r0 - lrow + lk8;
        f32x4 acc[4][2];
#pragma unroll
        for (int a = 0; a < 4; a++)
#pragma unroll
            for (int c = 0; c < 2; c++) acc[a][c] = (f32x4){0.f, 0.f, 0.f, 0.f};

        gload16(gB, &Bt[0][dbase]);                 // prologue stage k0=0
        for (int s = 0; s < ns; s++) {
            const int cur = s & 1;
            const int k0 = s * 64;
            if (s + 1 < ns) gload16(gB + k0 + 64, &Bt[cur ^ 1][dbase]);
            __syncthreads();                        // tile s resident
            if (k0 < wkmax) {
#pragma unroll
                for (int kk = 0; kk < 2; kk++) {
                    U af[4];
                    short8 bf2[2];
#pragma unroll
                    for (int mi = 0; mi < 4; mi++) {
                        int o = obase0 - mi * 16 + k0 + kk * 32;
                        uint adw = (uint)(o >> 1) + (uint)((o & 1) * 1088);
#pragma unroll
                        for (int q = 0; q < 4; q++) af[mi].d[q] = zsl[adw + q];
                    }
#pragma unroll
                    for (int ni = 0; ni < 2; ni++) {
                        int row = ni * 16 + lrow;
                        int c2 = (((kk * 4 + lk) ^ (row & 7))) * 8;
                        bf2[ni] = *reinterpret_cast<const short8*>(&Bt[cur][row * 64 + c2]);
                    }
#pragma unroll
                    for (int mi = 0; mi < 4; mi++)
#pragma unroll
                        for (int ni = 0; ni < 2; ni++)
                            acc[mi][ni] = __builtin_amdgcn_mfma_f32_16x16x32_bf16(af[mi].s8, bf2[ni], acc[mi][ni], 0, 0, 0);
                }
            }
            __syncthreads();                        // reads done before overwrite
        }
#pragma unroll
        for (int mi = 0; mi < 4; mi++)
#pragma unroll
            for (int ni = 0; ni < 2; ni++)
#pragma unroll
                for (int rr = 0; rr < 4; rr++) {
                    int row = r0 + mi * 16 + lk * 4 + rr;
                    int col = ebase + ni * 16 + lrow;
                    cv[((size_t)b * SEQ + row) * EMB + col] = f2bf(acc[mi][ni][rr]);
                }
    }
}

extern "C" void kernel_launch(void* const* d_in, const int* in_sizes, int n_in,
                              void* d_out, int out_size, void* d_ws, size_t ws_size,
                              hipStream_t stream) {
    const float* x   = (const float*)d_in[0];
    const float* W_A = (const float*)d_in[1];
    const float* W_V = (const float*)d_in[2];
    const float* W_O = (const float*)d_in[3];
    const float* b_O = (const float*)d_in[4];

    char* ws = (char*)d_ws;
    u16*   xb  = (u16*)(ws + 0);          // 8 MB   x bf16 [4096][1024]
    u16*   wvb = (u16*)(ws + 8388608);    // 2 MB   W_V bf16 [1024][1024]
    u16*   wob = (u16*)(ws + 10485760);   // 2 MB   W_O bf16
    float* zl  = (float*)(ws + 12582912); // 256 KB logits fp32 [B][H][S]
    u16*   zr  = (u16*)(ws + 12845056);   // 132 KB reversed softmax bf16 [B][H][ZP]
    u16*   vt2 = (u16*)(ws + 12980224);   // 8 MB   v^T bf16 [1024][B*S]
    u16*   cv  = (u16*)(ws + 21368832);   // 8 MB   conv out bf16 [4096][1024]

    cast_logits<<<2304, 256, 0, stream>>>(x, W_A, W_V, W_O, xb, wvb, wob, zl);
    // v^T[e][b*S+s] = sum_k W_V[e,k] * x[b,s,k]; blocks 512..543 do softmax
    gemm64<0, 0, true><<<544, 256, 0, stream>>>(wvb, xb, vt2, nullptr, nullptr,
                                                1024, 4096, 1024, zl, zr);
    conv2<<<256, 256, 0, stream>>>(zr, vt2, cv);
    gemm64<1, 1, false><<<512, 256, 0, stream>>>(cv, wob, nullptr, (float*)d_out, b_O,
                                                 4096, 1024, 1024, nullptr, nullptr);
}